// Round 9
// baseline (240.529 us; speedup 1.0000x reference)
//
#include <hip/hip_runtime.h>
#include <hip/hip_bf16.h>
#include <math.h>

typedef __attribute__((ext_vector_type(8))) short short8;
typedef __attribute__((ext_vector_type(4))) float f32x4;

#define CHUNK_B 16384         // bytes per 128-k fragment chunk (64 rows x 128 k bf16)
#define SLAB_A_F 8388608u     // 512 chunks per A feature
#define SLAB_B_F 4194304u     // 256 chunks per B feature
#define LROW 528              // LDS row stride bytes (512 + 16 pad)
#define K4S 28672             // floats per K replica (7 * 4096)

// round-to-nearest-even fp32 -> bf16 bits
__device__ __forceinline__ unsigned int bf16_rn(float x) {
    unsigned int u = __float_as_uint(x);
    return (u + 0x7FFFu + ((u >> 16) & 1u)) >> 16;
}

// ---------------------------------------------------------------------------
// Kernel 1: repack fp32 -> bf16 slab in MFMA fragment order via LDS transpose
// (R6-validated). Blocks 0-31 additionally zero the K replicas + counter
// when zeroK (stream-ordered before gram).
// ---------------------------------------------------------------------------
__global__ __launch_bounds__(256) void repack_kernel(
    const float* __restrict__ A, const float* __restrict__ B,
    char* __restrict__ slab, int nfA, int nfB,
    float* __restrict__ K4, int* __restrict__ counter, int zeroK)
{
    __shared__ __align__(16) char lds[64 * LROW];   // 33792 B

    if (zeroK && blockIdx.x < 32) {
        float* Kz = K4 + blockIdx.x * 3584;
        for (int i = threadIdx.x; i < 3584; i += 256) Kz[i] = 0.f;
        if (blockIdx.x == 0 && threadIdx.x == 0) *counter = 0;
    }

    const int uA = nfA * 256;
    const int u = blockIdx.x;
    const float* xbase; char* slabF; int D, span;
    if (u < uA) {
        int f = u >> 8; span = u & 255; D = 65536;
        xbase = A + (size_t)f * 64 * D;
        slabF = slab + (size_t)f * SLAB_A_F;
    } else {
        int v = u - uA;
        int f = v >> 7; span = v & 127; D = 32768;
        xbase = B + (size_t)f * 64 * D;
        slabF = slab + (size_t)nfA * SLAB_A_F + (size_t)f * SLAB_B_F;
    }
    const int k0 = span * 256;
    const int wave = threadIdx.x >> 6, lane = threadIdx.x & 63;

    // stage 1: 16 clustered row-loads (each one 1-KB contiguous granule)
    float4 v[16];
#pragma unroll
    for (int i = 0; i < 16; ++i) {
        int row = wave * 16 + i;
        v[i] = *(const float4*)(xbase + (size_t)row * D + k0 + lane * 4);
    }
#pragma unroll
    for (int i = 0; i < 16; ++i) {
        int row = wave * 16 + i;
        uint2 h;
        h.x = bf16_rn(v[i].x) | (bf16_rn(v[i].y) << 16);
        h.y = bf16_rn(v[i].z) | (bf16_rn(v[i].w) << 16);
        *(uint2*)(lds + row * LROW + lane * 8) = h;
    }
    __syncthreads();

    // stage 2: fragment gather from LDS + coalesced 1-KB stores
    const int m = lane & 15;
#pragma unroll
    for (int cc = 0; cc < 2; ++cc) {
        const int c = span * 2 + cc;
#pragma unroll
        for (int tm = 0; tm < 4; ++tm) {
            int row = tm * 16 + m;
            int kl = cc * 128 + wave * 32 + ((lane >> 4) << 3);
            short8 s = *(const short8*)(lds + row * LROW + kl * 2);
            *(short8*)(slabF + (size_t)c * CHUNK_B + wave * 4096
                       + tm * 1024 + lane * 16) = s;
        }
    }
}

// ---------------------------------------------------------------------------
// Kernel 2: Gram. Block = 2 consecutive chunks (feature-pure pairing).
// All 8 fragment loads (1-KB contiguous granules) issued up-front, then
// 32 MFMAs. LDS cross-wave reduce, atomicAdd into K replica blk&3
// (diagonal skipped -> diag stays 0).
// ---------------------------------------------------------------------------
__global__ __launch_bounds__(256) void gram_kernel(
    const char* __restrict__ slab, float* __restrict__ K4,
    int aChunks, int fOffset)
{
    __shared__ float kbuf[4096];
    const int blk = blockIdx.x;
    const int c0 = blk * 2;
    const int fl = (c0 < aChunks) ? (c0 >> 9)
                 : ((aChunks >> 9) + ((c0 - aChunks) >> 8));
    const int f = fl + fOffset;

    const int t = threadIdx.x;
    const int wave = t >> 6, lane = t & 63;
    const int m = lane & 15, quad = lane >> 4;
    const char* base = slab + (size_t)c0 * CHUNK_B + wave * 4096 + lane * 16;

    // ---- 8 clustered loads (both chunks) ----
    short8 fr[2][4];
#pragma unroll
    for (int c = 0; c < 2; ++c)
#pragma unroll
        for (int tm = 0; tm < 4; ++tm)
            fr[c][tm] = *(const short8*)(base + c * CHUNK_B + tm * 1024);

    f32x4 acc[4][4];
#pragma unroll
    for (int i = 0; i < 4; ++i)
#pragma unroll
        for (int j = 0; j < 4; ++j) acc[i][j] = (f32x4)0.f;

#pragma unroll
    for (int c = 0; c < 2; ++c)
#pragma unroll
        for (int tm = 0; tm < 4; ++tm)
#pragma unroll
            for (int tn = 0; tn < 4; ++tn)
                acc[tm][tn] = __builtin_amdgcn_mfma_f32_16x16x32_bf16(
                    fr[c][tm], fr[c][tn], acc[tm][tn], 0, 0, 0);

    // cross-wave reduce in LDS (C layout validated R2-R8)
    __syncthreads();
    if (wave == 0) {
#pragma unroll
        for (int tm = 0; tm < 4; ++tm)
#pragma unroll
            for (int tn = 0; tn < 4; ++tn)
#pragma unroll
                for (int r = 0; r < 4; ++r)
                    kbuf[(tm * 16 + quad * 4 + r) * 64 + tn * 16 + m] = acc[tm][tn][r];
    }
    __syncthreads();
    if (wave != 0) {
#pragma unroll
        for (int tm = 0; tm < 4; ++tm)
#pragma unroll
            for (int tn = 0; tn < 4; ++tn)
#pragma unroll
                for (int r = 0; r < 4; ++r)
                    atomicAdd(&kbuf[(tm * 16 + quad * 4 + r) * 64 + tn * 16 + m],
                              acc[tm][tn][r]);
    }
    __syncthreads();

    float* Kf = K4 + (size_t)(blk & 3) * K4S + (size_t)f * 4096;
    for (int e = t; e < 4096; e += 256)
        if ((e >> 6) != (e & 63)) atomicAdd(&Kf[e], kbuf[e]);
}

// ---------------------------------------------------------------------------
// Kernel 3: fused tail. Grid = 89 blocks: p<25 -> HSIC pair (fp64, replica
// sum); p in [25,89) -> CE row + logits copy. Arrival counter: the last
// block computes the final loss (no spinning).
// ---------------------------------------------------------------------------
__global__ __launch_bounds__(256) void tail_kernel(
    const float* __restrict__ K4, const float* __restrict__ logits,
    const int* __restrict__ target, float* __restrict__ out_copy,
    float* __restrict__ ce_rows, double* __restrict__ hsic,
    int* __restrict__ counter, float* __restrict__ out_loss)
{
    const int p = blockIdx.x;
    const int t = threadIdx.x;
    const int wave = t >> 6, lane = t & 63;
    __shared__ float red[256];
    __shared__ double wred[4];
    __shared__ double ri[64], rj[64];
    __shared__ int amLast;

    if (p < 25) {
        int i, j;
        if (p < 9) { i = p / 3; j = p % 3; }
        else       { int q = p - 9; i = 3 + q / 4; j = 3 + q % 4; }
        const float* Ki = K4 + (size_t)i * 4096;
        const float* Kj = K4 + (size_t)j * 4096;

        // tr(Ki Kj): coalesced strided loads, fp64 replica sum
        double local = 0.0;
        for (int e = t; e < 4096; e += 256) {
            double ki = (double)Ki[e] + (double)Ki[K4S + e]
                      + (double)Ki[2 * K4S + e] + (double)Ki[3 * K4S + e];
            double kj = (double)Kj[e] + (double)Kj[K4S + e]
                      + (double)Kj[2 * K4S + e] + (double)Kj[3 * K4S + e];
            local += ki * kj;
        }
        for (int off = 32; off > 0; off >>= 1)
            local += __shfl_down(local, off);
        if (lane == 0) wred[wave] = local;

        // rowsums: one full row per wave-instruction + shuffle reduce
        const float* M = (wave < 2) ? Ki : Kj;
        double* R = (wave < 2) ? ri : rj;
        const int r0 = (wave & 1) * 32;
        for (int rr = 0; rr < 32; ++rr) {
            int row = r0 + rr;
            int e = row * 64 + lane;
            double v = (double)M[e] + (double)M[K4S + e]
                     + (double)M[2 * K4S + e] + (double)M[3 * K4S + e];
            for (int off = 32; off > 0; off >>= 1)
                v += __shfl_down(v, off);
            if (lane == 0) R[row] = v;
        }
        __syncthreads();

        if (t == 0) {
            double tr = wred[0] + wred[1] + wred[2] + wred[3];
            double rr = 0.0, si = 0.0, sj = 0.0;
            for (int n = 0; n < 64; ++n) {
                rr += ri[n] * rj[n];
                si += ri[n];
                sj += rj[n];
            }
            const double N = 64.0;
            hsic[p] = (tr + si * sj / ((N - 1.0) * (N - 2.0))
                       - 2.0 * rr / (N - 2.0)) / (N * (N - 3.0));
        }
    } else {
        const int row = p - 25;
        const float* x = logits + row * 1000;

        float mx = -INFINITY;
        for (int i = t; i < 1000; i += 256) {
            float v = x[i];
            out_copy[row * 1000 + i] = v;
            mx = fmaxf(mx, v);
        }
        red[t] = mx; __syncthreads();
        for (int s = 128; s > 0; s >>= 1) {
            if (t < s) red[t] = fmaxf(red[t], red[t + s]);
            __syncthreads();
        }
        mx = red[0];
        __syncthreads();
        float ssum = 0.f;
        for (int i = t; i < 1000; i += 256) ssum += expf(x[i] - mx);
        red[t] = ssum; __syncthreads();
        for (int s = 128; s > 0; s >>= 1) {
            if (t < s) red[t] += red[t + s];
            __syncthreads();
        }
        if (t == 0) {
            double lse = (double)mx + log((double)red[0]);
            int tg = target[row];
            ce_rows[row] = (float)(-((double)x[tg] - lse));
        }
    }

    // ---- arrival: last block computes the loss ----
    __threadfence();
    __syncthreads();
    if (t == 0) amLast = (atomicAdd(counter, 1) == 88);
    __syncthreads();
    if (!amLast) return;
    __threadfence();

    if (t == 0) {
        double ce = 0.0;
        for (int n = 0; n < 64; ++n) ce += (double)ce_rows[n];
        ce /= 64.0;

        double cka_total = 0.0;
        for (int i = 0; i < 3; ++i)
            for (int j = 0; j < 3; ++j)
                cka_total += hsic[i * 3 + j] / sqrt(hsic[i * 3 + i] * hsic[j * 3 + j]);
        for (int i = 0; i < 4; ++i)
            for (int j = 0; j < 4; ++j)
                cka_total += hsic[9 + i * 4 + j]
                             / sqrt(hsic[9 + i * 4 + i] * hsic[9 + j * 4 + j]);

        out_loss[0] = (float)(ce + 0.1 * cka_total);
    }
}

// ---------------------------------------------------------------------------
extern "C" void kernel_launch(void* const* d_in, const int* in_sizes, int n_in,
                              void* d_out, int out_size, void* d_ws, size_t ws_size,
                              hipStream_t stream)
{
    const float* output  = (const float*)d_in[0];
    const int*   target  = (const int*)d_in[1];
    const float* feats_a = (const float*)d_in[2];
    const float* feats_b = (const float*)d_in[3];
    float* out = (float*)d_out;

    char* ws = (char*)d_ws;
    float*  K4      = (float*)ws;                 // 458752 B (4 replicas)
    float*  ce_rows = (float*)(ws + 458752);      // 256 B
    double* hsic    = (double*)(ws + 459008);     // 256 B
    int*    counter = (int*)(ws + 459264);        // 4 B
    char*   slab    = ws + 524288;

    const size_t slabAll = 3 * (size_t)SLAB_A_F + 4 * (size_t)SLAB_B_F; // 41.9 MB
    const size_t mainNeed = 524288 + slabAll;

    if (ws_size >= mainNeed) {
        // ------------- one-shot path: 3 dispatches total -------------
        hipLaunchKernelGGL(repack_kernel, dim3(1280), dim3(256), 0, stream,
                           feats_a, feats_b, slab, 3, 4, K4, counter, 1);
        hipLaunchKernelGGL(gram_kernel, dim3(1280), dim3(256), 0, stream,
                           (const char*)slab, K4, 1536, 0);
    } else {
        // ------------- per-feature fallback (~8.9 MB) -------------
        for (int f = 0; f < 7; ++f) {
            if (f < 3) {
                const float* X = feats_a + (size_t)f * 64 * 65536;
                hipLaunchKernelGGL(repack_kernel, dim3(256), dim3(256), 0, stream,
                                   X, (const float*)nullptr, slab, 1, 0,
                                   K4, counter, f == 0 ? 1 : 0);
                hipLaunchKernelGGL(gram_kernel, dim3(256), dim3(256), 0, stream,
                                   (const char*)slab, K4, 512, f);
            } else {
                const float* X = feats_b + (size_t)(f - 3) * 64 * 32768;
                hipLaunchKernelGGL(repack_kernel, dim3(128), dim3(256), 0, stream,
                                   (const float*)nullptr, X, slab, 0, 1,
                                   K4, counter, 0);
                hipLaunchKernelGGL(gram_kernel, dim3(128), dim3(256), 0, stream,
                                   (const char*)slab, K4, 0, f);
            }
        }
    }

    hipLaunchKernelGGL(tail_kernel, dim3(89), dim3(256), 0, stream,
                       K4, output, target, out + 1, ce_rows, hsic,
                       counter, out);
}

// Round 10
// 199.135 us; speedup vs baseline: 1.2079x; 1.2079x over previous
//
#include <hip/hip_runtime.h>
#include <hip/hip_bf16.h>
#include <math.h>

typedef __attribute__((ext_vector_type(8))) short short8;
typedef __attribute__((ext_vector_type(4))) float f32x4;

#define CHUNK_B 16384         // bytes per 128-k fragment chunk (64 rows x 128 k bf16)
#define SLAB_A_F 8388608u     // 512 chunks per A feature
#define SLAB_B_F 4194304u     // 256 chunks per B feature
#define LROW 528              // LDS row stride bytes (512 + 16 pad)
#define PSTRIDE 4160          // partial-tile stride in floats (4096 + 64, non-pow2)

// round-to-nearest-even fp32 -> bf16 bits
__device__ __forceinline__ unsigned int bf16_rn(float x) {
    unsigned int u = __float_as_uint(x);
    return (u + 0x7FFFu + ((u >> 16) & 1u)) >> 16;
}

// ---------------------------------------------------------------------------
// Kernel 1: repack fp32 -> bf16 slab in MFMA fragment order via LDS transpose
// (R6-validated; ~3 TB/s). Block 0 zeroes the tail arrival counter.
// ---------------------------------------------------------------------------
__global__ __launch_bounds__(256) void repack_kernel(
    const float* __restrict__ A, const float* __restrict__ B,
    char* __restrict__ slab, int nfA, int nfB,
    int* __restrict__ counter, int zeroCnt)
{
    __shared__ __align__(16) char lds[64 * LROW];   // 33792 B

    if (zeroCnt && blockIdx.x == 0 && threadIdx.x == 0) *counter = 0;

    const int uA = nfA * 256;
    const int u = blockIdx.x;
    const float* xbase; char* slabF; int D, span;
    if (u < uA) {
        int f = u >> 8; span = u & 255; D = 65536;
        xbase = A + (size_t)f * 64 * D;
        slabF = slab + (size_t)f * SLAB_A_F;
    } else {
        int v = u - uA;
        int f = v >> 7; span = v & 127; D = 32768;
        xbase = B + (size_t)f * 64 * D;
        slabF = slab + (size_t)nfA * SLAB_A_F + (size_t)f * SLAB_B_F;
    }
    const int k0 = span * 256;
    const int wave = threadIdx.x >> 6, lane = threadIdx.x & 63;

    // stage 1: 16 clustered row-loads (each one 1-KB contiguous granule)
    float4 v[16];
#pragma unroll
    for (int i = 0; i < 16; ++i) {
        int row = wave * 16 + i;
        v[i] = *(const float4*)(xbase + (size_t)row * D + k0 + lane * 4);
    }
#pragma unroll
    for (int i = 0; i < 16; ++i) {
        int row = wave * 16 + i;
        uint2 h;
        h.x = bf16_rn(v[i].x) | (bf16_rn(v[i].y) << 16);
        h.y = bf16_rn(v[i].z) | (bf16_rn(v[i].w) << 16);
        *(uint2*)(lds + row * LROW + lane * 8) = h;
    }
    __syncthreads();

    // stage 2: fragment gather from LDS + coalesced 1-KB stores
    const int m = lane & 15;
#pragma unroll
    for (int cc = 0; cc < 2; ++cc) {
        const int c = span * 2 + cc;
#pragma unroll
        for (int tm = 0; tm < 4; ++tm) {
            int row = tm * 16 + m;
            int kl = cc * 128 + wave * 32 + ((lane >> 4) << 3);
            short8 s = *(const short8*)(lds + row * LROW + kl * 2);
            *(short8*)(slabF + (size_t)c * CHUNK_B + wave * 4096
                       + tm * 1024 + lane * 16) = s;
        }
    }
}

// ---------------------------------------------------------------------------
// Kernel 2: Gram. Block = 4 consecutive chunks. ALL 16 fragment loads
// (1-KB contiguous granules, fully independent) issued up-front -> 16-deep
// MLP like repack; then 64 MFMAs; LDS cross-wave reduce; PLAIN coalesced
// stores of the partial tile (NO global atomics).
// ---------------------------------------------------------------------------
__global__ __launch_bounds__(256) void gram_kernel(
    const char* __restrict__ slab, float* __restrict__ partials)
{
    __shared__ float kbuf[4096];
    const int blk = blockIdx.x;
    const int t = threadIdx.x;
    const int wave = t >> 6, lane = t & 63;
    const int m = lane & 15, quad = lane >> 4;
    const char* base = slab + (size_t)blk * 4 * CHUNK_B + wave * 4096 + lane * 16;

    // ---- 16 clustered independent loads ----
    short8 fr[4][4];
#pragma unroll
    for (int c = 0; c < 4; ++c)
#pragma unroll
        for (int tm = 0; tm < 4; ++tm)
            fr[c][tm] = *(const short8*)(base + c * CHUNK_B + tm * 1024);

    f32x4 acc[4][4];
#pragma unroll
    for (int i = 0; i < 4; ++i)
#pragma unroll
        for (int j = 0; j < 4; ++j) acc[i][j] = (f32x4)0.f;

#pragma unroll
    for (int c = 0; c < 4; ++c)
#pragma unroll
        for (int tm = 0; tm < 4; ++tm)
#pragma unroll
            for (int tn = 0; tn < 4; ++tn)
                acc[tm][tn] = __builtin_amdgcn_mfma_f32_16x16x32_bf16(
                    fr[c][tm], fr[c][tn], acc[tm][tn], 0, 0, 0);

    // cross-wave reduce in LDS (C layout validated R2-R9)
    __syncthreads();
    if (wave == 0) {
#pragma unroll
        for (int tm = 0; tm < 4; ++tm)
#pragma unroll
            for (int tn = 0; tn < 4; ++tn)
#pragma unroll
                for (int r = 0; r < 4; ++r)
                    kbuf[(tm * 16 + quad * 4 + r) * 64 + tn * 16 + m] = acc[tm][tn][r];
    }
    __syncthreads();
    if (wave != 0) {
#pragma unroll
        for (int tm = 0; tm < 4; ++tm)
#pragma unroll
            for (int tn = 0; tn < 4; ++tn)
#pragma unroll
                for (int r = 0; r < 4; ++r)
                    atomicAdd(&kbuf[(tm * 16 + quad * 4 + r) * 64 + tn * 16 + m],
                              acc[tm][tn][r]);
    }
    __syncthreads();

    // plain coalesced stores (1-KB granules)
    float4* outp = (float4*)(partials + (size_t)blk * PSTRIDE);
    const float4* kb4 = (const float4*)kbuf;
    for (int e = t; e < 1024; e += 256) outp[e] = kb4[e];
}

// ---------------------------------------------------------------------------
// Kernel 3: reduce partial tiles -> K[f] (fp64 accumulate), zero diagonal.
// Block = (feature, 64-float slice). Loads are lane-contiguous 256-B
// granules, j-iterations independent -> deep clusters.
// singleF < 0: grid 448 (one-shot). Else grid 64, tiles at base 0.
// ---------------------------------------------------------------------------
__global__ __launch_bounds__(256) void reduce_kernel(
    const float* __restrict__ partials, float* __restrict__ K, int singleF)
{
    __shared__ double red[256];
    int f, slice, base, cnt;
    if (singleF < 0) {
        f = blockIdx.x >> 6; slice = blockIdx.x & 63;
        base = (f < 3) ? f * 128 : 384 + (f - 3) * 64;
        cnt  = (f < 3) ? 128 : 64;
    } else {
        f = singleF; slice = blockIdx.x; base = 0;
        cnt = (f < 3) ? 128 : 64;
    }
    const int lane = threadIdx.x & 63, jg = threadIdx.x >> 6;
    const float* src = partials + slice * 64 + lane;

    double s0 = 0.0, s1 = 0.0, s2 = 0.0, s3 = 0.0;
    for (int j = jg; j + 12 < cnt; j += 16) {
        s0 += (double)src[(size_t)(base + j)      * PSTRIDE];
        s1 += (double)src[(size_t)(base + j + 4)  * PSTRIDE];
        s2 += (double)src[(size_t)(base + j + 8)  * PSTRIDE];
        s3 += (double)src[(size_t)(base + j + 12) * PSTRIDE];
    }
    if (cnt == 64 || cnt == 128) {} // cnt divisible by 16: no remainder
    red[threadIdx.x] = (s0 + s1) + (s2 + s3);
    __syncthreads();
    if (jg == 0) {
        double tot = red[threadIdx.x] + red[threadIdx.x + 64]
                   + red[threadIdx.x + 128] + red[threadIdx.x + 192];
        int e = slice * 64 + lane;
        int rr = e >> 6, cc = e & 63;
        K[f * 4096 + e] = (rr == cc) ? 0.f : (float)tot;
    }
}

// ---------------------------------------------------------------------------
// Kernel 4: fused tail. Grid = 89 blocks: p<25 -> HSIC pair (fp64);
// p in [25,89) -> CE row + logits copy. Last-arriving block -> final loss.
// ---------------------------------------------------------------------------
__global__ __launch_bounds__(256) void tail_kernel(
    const float* __restrict__ K, const float* __restrict__ logits,
    const int* __restrict__ target, float* __restrict__ out_copy,
    float* __restrict__ ce_rows, double* __restrict__ hsic,
    int* __restrict__ counter, float* __restrict__ out_loss)
{
    const int p = blockIdx.x;
    const int t = threadIdx.x;
    const int wave = t >> 6, lane = t & 63;
    __shared__ float red[256];
    __shared__ double wred[4];
    __shared__ double ri[64], rj[64];
    __shared__ int amLast;

    if (p < 25) {
        int i, j;
        if (p < 9) { i = p / 3; j = p % 3; }
        else       { int q = p - 9; i = 3 + q / 4; j = 3 + q % 4; }
        const float* Ki = K + (size_t)i * 4096;
        const float* Kj = K + (size_t)j * 4096;

        // tr(Ki Kj): coalesced strided loads + shuffle reduce
        double local = 0.0;
#pragma unroll 4
        for (int e = t; e < 4096; e += 256)
            local += (double)Ki[e] * (double)Kj[e];
        for (int off = 32; off > 0; off >>= 1)
            local += __shfl_down(local, off);
        if (lane == 0) wred[wave] = local;

        // rowsums: one full row per wave-instruction + shuffle reduce
        const float* M = (wave < 2) ? Ki : Kj;
        double* R = (wave < 2) ? ri : rj;
        const int r0 = (wave & 1) * 32;
        for (int rr = 0; rr < 32; ++rr) {
            int row = r0 + rr;
            double v = (double)M[row * 64 + lane];
            for (int off = 32; off > 0; off >>= 1)
                v += __shfl_down(v, off);
            if (lane == 0) R[row] = v;
        }
        __syncthreads();

        if (t == 0) {
            double tr = wred[0] + wred[1] + wred[2] + wred[3];
            double rr = 0.0, si = 0.0, sj = 0.0;
            for (int n = 0; n < 64; ++n) {
                rr += ri[n] * rj[n];
                si += ri[n];
                sj += rj[n];
            }
            const double N = 64.0;
            hsic[p] = (tr + si * sj / ((N - 1.0) * (N - 2.0))
                       - 2.0 * rr / (N - 2.0)) / (N * (N - 3.0));
        }
    } else {
        const int row = p - 25;
        const float* x = logits + row * 1000;

        float mx = -INFINITY;
        for (int i = t; i < 1000; i += 256) {
            float v = x[i];
            out_copy[row * 1000 + i] = v;
            mx = fmaxf(mx, v);
        }
        red[t] = mx; __syncthreads();
        for (int s = 128; s > 0; s >>= 1) {
            if (t < s) red[t] = fmaxf(red[t], red[t + s]);
            __syncthreads();
        }
        mx = red[0];
        __syncthreads();
        float ssum = 0.f;
        for (int i = t; i < 1000; i += 256) ssum += expf(x[i] - mx);
        red[t] = ssum; __syncthreads();
        for (int s = 128; s > 0; s >>= 1) {
            if (t < s) red[t] += red[t + s];
            __syncthreads();
        }
        if (t == 0) {
            double lse = (double)mx + log((double)red[0]);
            int tg = target[row];
            ce_rows[row] = (float)(-((double)x[tg] - lse));
        }
    }

    // ---- arrival: last block computes the loss ----
    __threadfence();
    __syncthreads();
    if (t == 0) amLast = (atomicAdd(counter, 1) == 88);
    __syncthreads();
    if (!amLast) return;
    __threadfence();

    if (t == 0) {
        double ce = 0.0;
        for (int n = 0; n < 64; ++n) ce += (double)ce_rows[n];
        ce /= 64.0;

        double cka_total = 0.0;
        for (int i = 0; i < 3; ++i)
            for (int j = 0; j < 3; ++j)
                cka_total += hsic[i * 3 + j] / sqrt(hsic[i * 3 + i] * hsic[j * 3 + j]);
        for (int i = 0; i < 4; ++i)
            for (int j = 0; j < 4; ++j)
                cka_total += hsic[9 + i * 4 + j]
                             / sqrt(hsic[9 + i * 4 + i] * hsic[9 + j * 4 + j]);

        out_loss[0] = (float)(ce + 0.1 * cka_total);
    }
}

// ---------------------------------------------------------------------------
extern "C" void kernel_launch(void* const* d_in, const int* in_sizes, int n_in,
                              void* d_out, int out_size, void* d_ws, size_t ws_size,
                              hipStream_t stream)
{
    const float* output  = (const float*)d_in[0];
    const int*   target  = (const int*)d_in[1];
    const float* feats_a = (const float*)d_in[2];
    const float* feats_b = (const float*)d_in[3];
    float* out = (float*)d_out;

    char* ws = (char*)d_ws;
    float*  K       = (float*)ws;                 // 114688 B
    float*  ce_rows = (float*)(ws + 114688);      // 256 B
    double* hsic    = (double*)(ws + 114944);     // 256 B
    int*    counter = (int*)(ws + 115200);        // 4 B
    char*   slab    = ws + 131072;

    const size_t slabAll = 3 * (size_t)SLAB_A_F + 4 * (size_t)SLAB_B_F; // 41.9 MB
    const size_t partAll = (size_t)640 * PSTRIDE * 4;                   // 10.65 MB
    const size_t mainNeed = 131072 + slabAll + partAll;

    if (ws_size >= mainNeed) {
        // ---------- one-shot path: 4 dispatches ----------
        float* partials = (float*)(slab + slabAll);
        hipLaunchKernelGGL(repack_kernel, dim3(1280), dim3(256), 0, stream,
                           feats_a, feats_b, slab, 3, 4, counter, 1);
        hipLaunchKernelGGL(gram_kernel, dim3(640), dim3(256), 0, stream,
                           (const char*)slab, partials);
        hipLaunchKernelGGL(reduce_kernel, dim3(448), dim3(256), 0, stream,
                           partials, K, -1);
    } else {
        // ---------- per-feature fallback (~10.7 MB) ----------
        float* partials = (float*)(slab + SLAB_A_F);
        for (int f = 0; f < 7; ++f) {
            if (f < 3) {
                const float* X = feats_a + (size_t)f * 64 * 65536;
                hipLaunchKernelGGL(repack_kernel, dim3(256), dim3(256), 0, stream,
                                   X, (const float*)nullptr, slab, 1, 0,
                                   counter, f == 0 ? 1 : 0);
                hipLaunchKernelGGL(gram_kernel, dim3(128), dim3(256), 0, stream,
                                   (const char*)slab, partials);
            } else {
                const float* X = feats_b + (size_t)(f - 3) * 64 * 32768;
                hipLaunchKernelGGL(repack_kernel, dim3(128), dim3(256), 0, stream,
                                   (const float*)nullptr, X, slab, 0, 1,
                                   counter, 0);
                hipLaunchKernelGGL(gram_kernel, dim3(64), dim3(256), 0, stream,
                                   (const char*)slab, partials);
            }
            hipLaunchKernelGGL(reduce_kernel, dim3(64), dim3(256), 0, stream,
                               partials, K, f);
        }
    }

    hipLaunchKernelGGL(tail_kernel, dim3(89), dim3(256), 0, stream,
                       K, output, target, out + 1, ce_rows, hsic,
                       counter, out);
}